// Round 1
// baseline (74.180 us; speedup 1.0000x reference)
//
#include <hip/hip_runtime.h>
#include <hip/hip_bf16.h>
#include <math.h>

typedef __attribute__((ext_vector_type(8))) short bf16x8;
typedef __attribute__((ext_vector_type(4))) float f32x4;

#define NB 16
#define NM 16
#define NN 32
#define NT 80

__device__ __forceinline__ short f2bf(float f) {
  // round-to-nearest-even f32 -> bf16 (finite inputs only)
  unsigned u = __float_as_uint(f);
  u += 0x7fffu + ((u >> 16) & 1u);
  return (short)(u >> 16);
}

// ---------------- kernel 0: weights head (data-independent: enc_in = ones) ---
__global__ void weights_kernel(const float* __restrict__ wd_w1,
                               const float* __restrict__ wd_b1,
                               const float* __restrict__ wd_w2,
                               const float* __restrict__ wd_b2,
                               float* __restrict__ ws_weights,
                               float* __restrict__ out) {
  __shared__ float sh[64];
  int j = threadIdx.x;
  if (j < 64) {
    float acc = wd_b1[j];
    for (int i = 0; i < 256; ++i) acc += wd_w1[i * 64 + j];
    sh[j] = acc > 0.f ? acc : expm1f(acc);  // elu
  }
  __syncthreads();
  if (j < 8) {
    float acc = wd_b2[j];
    for (int k = 0; k < 64; ++k) acc += sh[k] * wd_w2[k * 8 + j];
    float sp = log1pf(__expf(acc));  // softplus
    ws_weights[j] = sp;
    for (int b = 0; b < NB; ++b) out[NB * NM + b * 8 + j] = sp;  // weights output
  }
}

// ---------------- kernel 1: main fused score kernel -------------------------
__global__ __launch_bounds__(256, 1) void score_kernel(
    const float* __restrict__ ego_traj,      // [B][M][T][6]
    const float* __restrict__ agents_traj,   // [B][M][N][T][3]
    const float* __restrict__ agents_states, // [B][N][11]
    const float* __restrict__ enc_w1, const float* __restrict__ enc_b1,
    const float* __restrict__ enc_w2, const float* __restrict__ enc_b2,
    const float* __restrict__ dec_w1, const float* __restrict__ dec_b1,
    const float* __restrict__ dec_w2, const float* __restrict__ dec_b2,
    const float* __restrict__ wts,           // 8 floats (from ws)
    float* __restrict__ out_scores)          // [B*M]
{
  __shared__ float s_traj[NT][NN][3];                 // 30720 B, [t][n][c]
  __shared__ __align__(16) short s_hidden[2][NN * 64]; // 8192 B, swizzled bf16
  __shared__ float s_ego[NT][8];                      // ex,ey,eh,evx,evy
  __shared__ float s_feat[256];
  __shared__ float s_dh[64];
  __shared__ float s_r0[NT], s_r1[NT], s_r2[NT], s_r3[NT];
  __shared__ float s_mask[NN];
  __shared__ float s_collred[NN];
  __shared__ float s_hard[4];
  __shared__ float s_inter[4];
  __shared__ float s_misc[2];  // [0]=ego sum (mask), [1]=coll

  const int bm = blockIdx.x;
  const int b = bm >> 4;
  const int tid = threadIdx.x;
  const int lane = tid & 63;
  const int wv = tid >> 6;

  // ---- phase A: stage traj, per-t ego features, agent mask ----
  {
    const float* src = agents_traj + (size_t)bm * (NN * NT * 3);
    for (int i = tid; i < NN * NT * 3; i += 256) {
      int n = i / (NT * 3);
      int r = i - n * (NT * 3);
      int t = r / 3;
      int c = r - t * 3;
      s_traj[t][n][c] = src[i];
    }
    if (tid < NT) {
      int t = tid;
      const float* e = ego_traj + ((size_t)bm * NT + t) * 6;
      float ex = e[0], ey = e[1], eh = e[2], spd = e[3], acc = e[4], cur = e[5];
      float ce = __cosf(eh), se = __sinf(eh);
      s_ego[t][0] = ex; s_ego[t][1] = ey; s_ego[t][2] = eh;
      s_ego[t][3] = spd * ce;  // evx
      s_ego[t][4] = spd * se;  // evy
      s_r0[t] = spd;
      s_r1[t] = acc;
      s_r2[t] = fabsf(spd * spd * cur);
      s_r3[t] = ex + ey + eh + spd + acc + cur;  // for ego_mask
    }
    if (tid >= 128 && tid < 128 + NN) {
      int n = tid - 128;
      const float* st = agents_states + ((size_t)b * NN + n) * 11;
      float s = 0.f;
      for (int i = 0; i < 11; ++i) s += st[i];
      s_mask[n] = (s != 0.f) ? 1.f : 0.f;
    }
  }
  __syncthreads();

  // ---- phase B: hard-feature reductions + per-thread constants ----
  if (tid == 0) {
    float s = 0.f; for (int t = 0; t < NT; ++t) s += s_r0[t];
    s_hard[0] = -fminf(fmaxf(s * (1.f / NT), 0.f), 15.f) * (1.f / 15.f);
  } else if (tid == 1) {
    float s = 0.f; for (int t = 0; t < NT; ++t) s += fabsf(s_r1[t]);
    s_hard[1] = fminf(fmaxf(s * (1.f / NT), 0.f), 4.f) * 0.25f;
  } else if (tid == 2) {
    float s = 0.f;
    for (int t = 0; t < NT; ++t) {
      int th = t ? t : 1;
      s += fabsf((s_r1[th] - s_r1[th - 1]) * 10.f);
    }
    s_hard[2] = fminf(fmaxf(s * (1.f / NT), 0.f), 6.f) * (1.f / 6.f);
  } else if (tid == 3) {
    float s = 0.f; for (int t = 0; t < NT; ++t) s += s_r2[t];
    s_hard[3] = fminf(fmaxf(s * (1.f / NT), 0.f), 5.f) * 0.2f;
  } else if (tid == 4) {
    float s = 0.f; for (int t = 0; t < NT; ++t) s += s_r3[t];
    s_misc[0] = s;
  }

  const int n = tid >> 3;   // agent handled by this thread in GEMM1
  const int jg = tid & 7;
  const int j0 = jg * 8;
  const float mask_n = s_mask[n];

  // enc_w1 rows 0..4 (rel features) -> registers
  float w1r[5][8];
#pragma unroll
  for (int i = 0; i < 5; ++i)
#pragma unroll
    for (int jj = 0; jj < 8; ++jj)
      w1r[i][jj] = enc_w1[i * 64 + j0 + jj];

  // baseB = mask * (agent_states[6:11] @ enc_w1[5:10]) + enc_b1
  float baseB[8];
  {
    const float* st = agents_states + ((size_t)b * NN + n) * 11 + 6;
    float a0 = st[0], a1 = st[1], a2 = st[2], a3 = st[3], a4 = st[4];
#pragma unroll
    for (int jj = 0; jj < 8; ++jj) {
      float acc = a0 * enc_w1[5 * 64 + j0 + jj] + a1 * enc_w1[6 * 64 + j0 + jj] +
                  a2 * enc_w1[7 * 64 + j0 + jj] + a3 * enc_w1[8 * 64 + j0 + jj] +
                  a4 * enc_w1[9 * 64 + j0 + jj];
      baseB[jj] = mask_n * acc + enc_b1[j0 + jj];
    }
  }

  // enc_w2 B-fragments in registers: wave wv owns cols [wv*64, wv*64+64)
  // B-frag layout (16x16x32): lane holds B[k=(l>>4)*8+j][col=l&15]
  bf16x8 Bf[4][2];
  {
    const int colb = lane & 15;
    const int krow = (lane >> 4) * 8;
#pragma unroll
    for (int ct = 0; ct < 4; ++ct) {
      int col = wv * 64 + ct * 16 + colb;
#pragma unroll
      for (int kt = 0; kt < 2; ++kt) {
#pragma unroll
        for (int j = 0; j < 8; ++j) {
          int k = kt * 32 + krow + j;
          Bf[ct][kt][j] = f2bf(enc_w2[k * 256 + col]);
        }
      }
    }
  }

  // swizzled hidden-tile addresses: byte ^= (row&7)<<4 spreads banks (G4)
  const int wbyte = (n * 128 + j0 * 2) ^ ((n & 7) << 4);
  int abyte[2][2];
  {
    int nb = lane & 15;
    int kb = (lane >> 4) * 16;
#pragma unroll
    for (int rt = 0; rt < 2; ++rt) {
      int row = rt * 16 + nb;
#pragma unroll
      for (int kt = 0; kt < 2; ++kt)
        abyte[rt][kt] = (row * 128 + kt * 64 + kb) ^ ((row & 7) << 4);
    }
  }

  float collacc = 0.f;

  // rel features + GEMM1(K=5) + relu + bf16 -> swizzled LDS tile
  auto compute_hidden = [&](int t, int buf) {
    float ex = s_ego[t][0], ey = s_ego[t][1], eh = s_ego[t][2];
    float evx = s_ego[t][3], evy = s_ego[t][4];
    float ax = s_traj[t][n][0], ay = s_traj[t][n][1], ah = s_traj[t][n][2];
    int th = t ? t : 1;
    float avx = (s_traj[th][n][0] - s_traj[th - 1][n][0]) * 10.f;
    float avy = (s_traj[th][n][1] - s_traj[th - 1][n][1]) * 10.f;
    float ryr = ah - eh;
    // wrap to (-pi,pi] == atan2(sin,cos)
    float w = ryr - 6.283185307179586f * rintf(ryr * 0.15915494309189535f);
    float cy = __cosf(ryr), sy = __sinf(ryr);
    float dx = ax - ex, dy = ay - ey;
    float r0 = dx * cy * mask_n;
    float r1 = dy * sy * mask_n;
    float r2 = w * mask_n;
    float r3 = (avx - evx) * cy * mask_n;
    float r4 = (avy - evy) * sy * mask_n;
    if (jg == 0) {  // coll only once per (n,t) (8x redundant rel otherwise)
      collacc += __expf(-0.2f * (dx * dx + dy * dy)) * mask_n;
    }
    bf16x8 hv;
#pragma unroll
    for (int jj = 0; jj < 8; ++jj) {
      float pre = baseB[jj] + r0 * w1r[0][jj] + r1 * w1r[1][jj] +
                  r2 * w1r[2][jj] + r3 * w1r[3][jj] + r4 * w1r[4][jj];
      hv[jj] = f2bf(fmaxf(pre, 0.f));
    }
    *reinterpret_cast<bf16x8*>(reinterpret_cast<char*>(&s_hidden[buf][0]) + wbyte) = hv;
  };

  compute_hidden(0, 0);
  __syncthreads();

  float macc[4] = {0.f, 0.f, 0.f, 0.f};

  for (int t = 0; t < NT; ++t) {
    const int buf = t & 1;
    const char* hb = reinterpret_cast<const char*>(&s_hidden[buf][0]);
    bf16x8 a00 = *reinterpret_cast<const bf16x8*>(hb + abyte[0][0]);
    bf16x8 a01 = *reinterpret_cast<const bf16x8*>(hb + abyte[0][1]);
    bf16x8 a10 = *reinterpret_cast<const bf16x8*>(hb + abyte[1][0]);
    bf16x8 a11 = *reinterpret_cast<const bf16x8*>(hb + abyte[1][1]);

    if (t + 1 < NT) compute_hidden(t + 1, buf ^ 1);  // ping-pong overlap

#pragma unroll
    for (int ct = 0; ct < 4; ++ct) {
      f32x4 c0 = {0.f, 0.f, 0.f, 0.f}, c1 = {0.f, 0.f, 0.f, 0.f};
      c0 = __builtin_amdgcn_mfma_f32_16x16x32_bf16(a00, Bf[ct][0], c0, 0, 0, 0);
      c0 = __builtin_amdgcn_mfma_f32_16x16x32_bf16(a01, Bf[ct][1], c0, 0, 0, 0);
      c1 = __builtin_amdgcn_mfma_f32_16x16x32_bf16(a10, Bf[ct][0], c1, 0, 0, 0);
      c1 = __builtin_amdgcn_mfma_f32_16x16x32_bf16(a11, Bf[ct][1], c1, 0, 0, 0);
      // max over n: 4 regs x 2 row-tiles, then lanes l^16, l^32 (same col)
      float v = fmaxf(fmaxf(fmaxf(c0[0], c1[0]), fmaxf(c0[1], c1[1])),
                      fmaxf(fmaxf(c0[2], c1[2]), fmaxf(c0[3], c1[3])));
      v = fmaxf(v, __shfl_xor(v, 16));
      v = fmaxf(v, __shfl_xor(v, 32));
      macc[ct] += v;
    }
    __syncthreads();
  }

  // ---- epilogue ----
  if (lane < 16) {
#pragma unroll
    for (int ct = 0; ct < 4; ++ct) {
      int col = wv * 64 + ct * 16 + lane;
      s_feat[col] = macc[ct] * (1.f / NT) + enc_b2[col];
    }
  }
  if (jg == 0) s_collred[n] = collacc;
  __syncthreads();

  if (tid < 64) {
    float a0 = 0.f, a1 = 0.f, a2 = 0.f, a3 = 0.f;
    for (int i = 0; i < 256; i += 4) {
      a0 += s_feat[i + 0] * dec_w1[(i + 0) * 64 + tid];
      a1 += s_feat[i + 1] * dec_w1[(i + 1) * 64 + tid];
      a2 += s_feat[i + 2] * dec_w1[(i + 2) * 64 + tid];
      a3 += s_feat[i + 3] * dec_w1[(i + 3) * 64 + tid];
    }
    float acc = dec_b1[tid] + ((a0 + a1) + (a2 + a3));
    s_dh[tid] = acc > 0.f ? acc : expm1f(acc);  // elu
  } else if (tid == 64) {
    float c = 0.f;
    for (int i = 0; i < NN; ++i) c += s_collred[i];
    s_misc[1] = c;
  }
  __syncthreads();

  if (tid < 4) {
    float acc = dec_b2[tid];
    for (int k = 0; k < 64; ++k) acc += s_dh[k] * dec_w2[k * 4 + tid];
    s_inter[tid] = 1.f / (1.f + __expf(-acc));  // sigmoid
  }
  __syncthreads();

  if (tid == 0) {
    float sc = 0.f;
#pragma unroll
    for (int i = 0; i < 4; ++i) sc += s_hard[i] * wts[i];
#pragma unroll
    for (int i = 0; i < 4; ++i) sc += s_inter[i] * wts[4 + i];
    sc = -sc - 10.f * s_misc[1];
    if (s_misc[0] == 0.f) sc = -INFINITY;
    out_scores[bm] = sc;
  }
}

extern "C" void kernel_launch(void* const* d_in, const int* in_sizes, int n_in,
                              void* d_out, int out_size, void* d_ws, size_t ws_size,
                              hipStream_t stream) {
  const float* ego_traj      = (const float*)d_in[0];
  // d_in[1] = ego_encoding (unused: enc_in = ones in reference)
  const float* agents_traj   = (const float*)d_in[2];
  const float* agents_states = (const float*)d_in[3];
  const float* enc_w1 = (const float*)d_in[4];
  const float* enc_b1 = (const float*)d_in[5];
  const float* enc_w2 = (const float*)d_in[6];
  const float* enc_b2 = (const float*)d_in[7];
  const float* dec_w1 = (const float*)d_in[8];
  const float* dec_b1 = (const float*)d_in[9];
  const float* dec_w2 = (const float*)d_in[10];
  const float* dec_b2 = (const float*)d_in[11];
  const float* wd_w1 = (const float*)d_in[12];
  const float* wd_b1 = (const float*)d_in[13];
  const float* wd_w2 = (const float*)d_in[14];
  const float* wd_b2 = (const float*)d_in[15];
  // d_in[16] = timesteps (always 80 for this problem)

  float* out = (float*)d_out;
  float* ws_weights = (float*)d_ws;

  weights_kernel<<<1, 64, 0, stream>>>(wd_w1, wd_b1, wd_w2, wd_b2, ws_weights, out);
  score_kernel<<<NB * NM, 256, 0, stream>>>(
      ego_traj, agents_traj, agents_states,
      enc_w1, enc_b1, enc_w2, enc_b2,
      dec_w1, dec_b1, dec_w2, dec_b2,
      ws_weights, out);
}